// Round 4
// baseline (706.881 us; speedup 1.0000x reference)
//
#include <hip/hip_runtime.h>

typedef _Float16 half8 __attribute__((ext_vector_type(8)));
typedef _Float16 half4 __attribute__((ext_vector_type(4)));
typedef float fx4 __attribute__((ext_vector_type(4)));

#define MFMA16(a,b,c) __builtin_amdgcn_mfma_f32_16x16x32_f16(a,b,c,0,0,0)

#define BN 4
#define CC 512
#define HH 56
#define WW 56
#define NQ 3136
#define OQ 784
#define NH 8
#define HD 64
#define NSEG 7
#define BGN (BN * NH * NQ)   // 100352

__device__ inline half8 h8z() {
    half8 v;
#pragma unroll
    for (int j = 0; j < 8; j++) v[j] = (_Float16)0.f;
    return v;
}

// async global->LDS, 16B per lane; LDS dest must be wave-uniform base,
// lanes land at base + lane*16 (linear). Source addr is per-lane.
__device__ __forceinline__ void glds16(const void* g, void* l) {
    __builtin_amdgcn_global_load_lds(
        (__attribute__((address_space(1))) const unsigned int*)g,
        (__attribute__((address_space(3))) unsigned int*)l, 16, 0, 0);
}

// ---- convert 4 fp32 weight mats -> fp16 (contiguous dsts); zero S2 -------
__global__ void cvt4_kernel(const float* __restrict__ a, const float* __restrict__ b,
                            const float* __restrict__ c, const float* __restrict__ d,
                            _Float16* __restrict__ o, float* __restrict__ S2) {
    if (blockIdx.x == 0 && blockIdx.y == 0 && threadIdx.x < 32) S2[threadIdx.x] = 0.f;
    int y = blockIdx.y;
    const float* s = (y == 0) ? a : (y == 1) ? b : (y == 2) ? c : d;
    int i = blockIdx.x * 256 + threadIdx.x;
    o[(size_t)y * 262144 + i] = (_Float16)s[i];
}

// ---- x (B,C,H*W) -> xf16 (B, NQ, C) fp16 (tiled transpose) ---------------
__global__ void xpose_kernel(const float* __restrict__ x, _Float16* __restrict__ xf) {
    __shared__ float t[32][33];
    int n0 = blockIdx.x * 32, c0 = blockIdx.y * 32, b = blockIdx.z;
    int tx = threadIdx.x, ty = threadIdx.y;
#pragma unroll
    for (int i = 0; i < 4; i++)
        t[ty + 8 * i][tx] = x[((size_t)(b * CC) + c0 + ty + 8 * i) * NQ + n0 + tx];
    __syncthreads();
#pragma unroll
    for (int i = 0; i < 4; i++)
        xf[((size_t)(b * NQ) + n0 + ty + 8 * i) * CC + c0 + tx] = (_Float16)t[tx][ty + 8 * i];
}

// ---- depthwise conv 3x3 s2 p1 + bias -> xsc (B, OQ, C) fp32 --------------
__global__ void dw_kernel(const float* __restrict__ x, const float* __restrict__ w,
                          const float* __restrict__ bias, float* __restrict__ xsc) {
    int cb = blockIdx.x, oy = blockIdx.y, b = blockIdx.z;
    int tx = threadIdx.x, ty = threadIdx.y;
    int c = cb * 16 + ty;
    float a = bias[c];
    const float* xp = x + ((size_t)(b * CC + c) * HH) * WW;
#pragma unroll
    for (int ky = 0; ky < 3; ky++) {
        int iy = 2 * oy - 1 + ky;
        if (iy < 0 || iy >= HH) continue;
#pragma unroll
        for (int kx = 0; kx < 3; kx++) {
            int ix = 2 * tx - 1 + kx;
            if (ix < 0 || ix >= WW) continue;
            a += xp[iy * WW + ix] * w[c * 9 + ky * 3 + kx];
        }
    }
    __shared__ float tile[28][17];
    tile[tx][ty] = a;
    __syncthreads();
    int lin = ty * 28 + tx;
    int oi = lin >> 4, ci = lin & 15;
    xsc[((size_t)(b * OQ) + oy * 28 + oi) * CC + cb * 16 + ci] = tile[oi][ci];
}

// ---- LayerNorm over C -> xs16 (B*OQ, C) fp16 -----------------------------
__global__ __launch_bounds__(256) void ln_kernel(const float* __restrict__ xsc,
        const float* __restrict__ g, const float* __restrict__ bb,
        _Float16* __restrict__ xs16) {
    int row = blockIdx.x;
    const float* rp = xsc + (size_t)row * CC;
    int t = threadIdx.x;
    float v0 = rp[t], v1 = rp[t + 256];
    float s = v0 + v1, ss = v0 * v0 + v1 * v1;
#pragma unroll
    for (int m = 1; m < 64; m <<= 1) {
        s += __shfl_xor(s, m, 64);
        ss += __shfl_xor(ss, m, 64);
    }
    __shared__ float red[8];
    int wv = t >> 6;
    if ((t & 63) == 0) { red[wv] = s; red[4 + wv] = ss; }
    __syncthreads();
    s = red[0] + red[1] + red[2] + red[3];
    ss = red[4] + red[5] + red[6] + red[7];
    float mean = s * (1.f / 512.f);
    float var = ss * (1.f / 512.f) - mean * mean;
    float rs = rsqrtf(var + 1e-5f);
    xs16[(size_t)row * CC + t] = (_Float16)((v0 - mean) * rs * g[t] + bb[t]);
    xs16[(size_t)row * CC + t + 256] = (_Float16)((v1 - mean) * rs * g[t + 256] + bb[t + 256]);
}

// ---- fused q/k/v projections, 64x64 tiles, K=512 NT ----------------------
// grid (196, 8, 3). T3 2-phase: global_load_lds (16B) + LDS dbuf, one
// barrier per K-tile; XOR-swizzled source (granule ^ row&7) keeps
// ds_read_b128 frag reads 2-way (free) without padding.
__global__ __launch_bounds__(256) void gemm_qkv(const _Float16* __restrict__ xf,
        const _Float16* __restrict__ xs, const _Float16* __restrict__ w4,
        _Float16* __restrict__ q16, _Float16* __restrict__ k16, _Float16* __restrict__ vT) {
    const int which = blockIdx.z;
    if (which && blockIdx.x >= 49) return;
    const _Float16* A = which ? xs : xf;
    const _Float16* Bw = w4 + (size_t)which * 262144;
    __shared__ _Float16 As[2][64 * 64];
    __shared__ _Float16 Bs[2][64 * 64];
    const int m0 = blockIdx.x * 64, n0 = blockIdx.y * 64;
    const int tid = threadIdx.x;
    const int lane = tid & 63, wv = tid >> 6;
    const int wm = (wv >> 1) * 32, wn = (wv & 1) * 32;
    const int l15 = lane & 15, quad = lane >> 4;
    fx4 acc[2][2];
#pragma unroll
    for (int i = 0; i < 2; i++)
#pragma unroll
        for (int j = 0; j < 2; j++) acc[i][j] = fx4{0.f, 0.f, 0.f, 0.f};

#define STAGEG(bf, kk)                                                       \
    {                                                                        \
        _Pragma("unroll") for (int i = 0; i < 2; i++) {                      \
            int id = tid + 256 * i;                                          \
            int r = id >> 3, gg = id & 7;                                    \
            int gs = gg ^ (r & 7);                                           \
            glds16(A + (size_t)(m0 + r) * 512 + (kk) + gs * 8,               \
                   &As[bf][(id & ~63) * 8]);                                 \
            glds16(Bw + (size_t)(n0 + r) * 512 + (kk) + gs * 8,              \
                   &Bs[bf][(id & ~63) * 8]);                                 \
        }                                                                    \
    }

    STAGEG(0, 0);
    __syncthreads();
    for (int kt = 0; kt < 8; kt++) {
        const int cur = kt & 1;
        if (kt < 7) STAGEG(cur ^ 1, (kt + 1) * 64);
#pragma unroll
        for (int ks = 0; ks < 2; ks++) {
            half8 af[2], bf[2];
#pragma unroll
            for (int s = 0; s < 2; s++) {
                int ra = wm + s * 16 + l15;
                int rb = wn + s * 16 + l15;
                af[s] = *(const half8*)(&As[cur][ra * 64 + ((ks * 4 + quad) ^ (ra & 7)) * 8]);
                bf[s] = *(const half8*)(&Bs[cur][rb * 64 + ((ks * 4 + quad) ^ (rb & 7)) * 8]);
            }
#pragma unroll
            for (int i = 0; i < 2; i++)
#pragma unroll
                for (int j = 0; j < 2; j++)
                    acc[i][j] = MFMA16(af[i], bf[j], acc[i][j]);
        }
        __syncthreads();
    }
#undef STAGEG

    if (which < 2) {
        _Float16* O = which ? k16 : q16;
#pragma unroll
        for (int i = 0; i < 2; i++)
#pragma unroll
            for (int j = 0; j < 2; j++) {
                int col = n0 + wn + j * 16 + l15;
#pragma unroll
                for (int e = 0; e < 4; e++) {
                    int row = m0 + wm + i * 16 + quad * 4 + e;
                    O[(size_t)row * 512 + col] = (_Float16)acc[i][j][e];
                }
            }
    } else {
        // vT[(b*8 + c/64)*64 + c%64][o]; 4 consecutive o -> packed 8B store
#pragma unroll
        for (int i = 0; i < 2; i++) {
            int row = m0 + wm + i * 16 + quad * 4;  // b*784 + o, multiple of 4
            int b = row / OQ;
            int o = row - b * OQ;
#pragma unroll
            for (int j = 0; j < 2; j++) {
                int c = n0 + wn + j * 16 + l15;
                half4 pk;
#pragma unroll
                for (int e = 0; e < 4; e++) pk[e] = (_Float16)acc[i][j][e];
                *(half4*)(vT + ((size_t)(b * NH + (c >> 6)) * HD + (c & 63)) * OQ + o) = pk;
            }
        }
    }
}

// ---- QK^T + head-mix + logit write (TILED layout) + partial Z / E2 -------
// grid (49 nblk, 7 oseg, 4 b), block 256 (4 waves, each a 16-row n-subtile)
// K-tile staging: global_load_lds + dbuf, ONE barrier per ot; source
// pre-swizzled (granule low3 ^ row&7) so bF ds_read_b128 is 2-way (free).
// L layout: 16n x 16o tiles -> pv reads one contiguous 1KB wave-load/chunk.
__global__ __launch_bounds__(256) void qk_mix(const _Float16* __restrict__ q16,
        const _Float16* __restrict__ k16, const float* __restrict__ tcw,
        const float* __restrict__ tcb, _Float16* __restrict__ L,
        float* __restrict__ Zpart, float* __restrict__ E2part) {
    __shared__ _Float16 kl[2][16 * 512];
    __shared__ float tcs[64];
    __shared__ float tbb[8];
    const int b = blockIdx.z, oseg = blockIdx.y, ob = oseg * 112;
    const int tid = threadIdx.x;
    const int wv = tid >> 6, lane = tid & 63, l15 = lane & 15, quad = lane >> 4;
    const int n0 = blockIdx.x * 64 + wv * 16;
    if (tid < 64) tcs[tid] = tcw[tid] * 0.125f;  // fold scale hd^-0.5
    else if (tid < 72) tbb[tid - 64] = tcb[tid - 64];

    half8 aF[8][2];
    const _Float16* qrow = q16 + ((size_t)(b * NQ + n0 + l15)) * 512;
#pragma unroll
    for (int h = 0; h < 8; h++)
#pragma unroll
        for (int ks = 0; ks < 2; ks++)
            aF[h][ks] = *(const half8*)(qrow + h * 64 + ks * 32 + quad * 8);

    float z[8][4], s2[8][4];
#pragma unroll
    for (int g = 0; g < 8; g++)
#pragma unroll
        for (int e = 0; e < 4; e++) { z[g][e] = 0.f; s2[g][e] = 0.f; }

#define STAGEK(bf, oo)                                                       \
    {                                                                        \
        const _Float16* kbp = k16 + ((size_t)(b * OQ + (oo))) * 512;         \
        _Pragma("unroll") for (int i = 0; i < 4; i++) {                      \
            int id = tid + 256 * i;                                          \
            int r = id >> 6, g16 = id & 63;                                  \
            int gs = (g16 & 56) | ((g16 & 7) ^ (r & 7));                     \
            glds16(kbp + (size_t)r * 512 + gs * 8, &kl[bf][(id & ~63) * 8]); \
        }                                                                    \
    }

    STAGEK(0, ob);
    __syncthreads();  // buf0 ready; also covers tcs/tbb init

    for (int ot = 0; ot < 7; ot++) {
        const int cur = ot & 1;
        if (ot < 6) STAGEK(cur ^ 1, ob + (ot + 1) * 16);  // overlap w/ compute
        int o0 = ob + ot * 16;
        fx4 s[8];
#pragma unroll
        for (int h = 0; h < 8; h++) {
            fx4 a = fx4{0.f, 0.f, 0.f, 0.f};
#pragma unroll
            for (int ks = 0; ks < 2; ks++) {
                int colg = h * 8 + ks * 4 + quad;
                int rg = (colg & 56) | ((colg & 7) ^ (l15 & 7));
                half8 bF = *(const half8*)(&kl[cur][l15 * 512 + rg * 8]);
                a = MFMA16(aF[h][ks], bF, a);
            }
            s[h] = a;
        }
#pragma unroll
        for (int g = 0; g < 8; g++) {
            size_t tb = (((size_t)(b * 8 + g) * 196 + (n0 >> 4)) * 49 + (o0 >> 4)) * 256
                        + (l15 >> 3) * 128 + (l15 & 7);
#pragma unroll
            for (int e = 0; e < 4; e++) {
                float v = tbb[g];
#pragma unroll
                for (int h = 0; h < 8; h++) v += tcs[g * 8 + h] * s[h][e];
                _Float16 vh = (_Float16)v;
                float vr = (float)vh;  // rounded value so Z matches pass 2 exactly
                float ex = __expf(vr);
                z[g][e] += ex;
                s2[g][e] += ex * ex;
                L[tb + (quad * 4 + e) * 8] = vh;
            }
        }
        __syncthreads();  // drains stage of buf cur^1 -> ready next ot
    }
#undef STAGEK

#pragma unroll
    for (int m = 1; m < 16; m <<= 1) {
#pragma unroll
        for (int g = 0; g < 8; g++)
#pragma unroll
            for (int e = 0; e < 4; e++) {
                z[g][e] += __shfl_xor(z[g][e], m, 64);
                s2[g][e] += __shfl_xor(s2[g][e], m, 64);
            }
    }
    if (l15 < 8) {
        int g = l15;
        size_t base = (size_t)oseg * BGN + (size_t)(b * 8 + g) * NQ + n0 + quad * 4;
#pragma unroll
        for (int e = 0; e < 4; e++) {
            Zpart[base + e] = z[g][e];
            E2part[base + e] = s2[g][e];
        }
    }
}

// ---- sum partials: Zinv per row, S2[b,g] global --------------------------
__global__ __launch_bounds__(256) void zfin_kernel(const float* __restrict__ Zpart,
        const float* __restrict__ E2part, float* __restrict__ Zinv, float* __restrict__ S2) {
    int i = blockIdx.x * 256 + threadIdx.x;  // 0..BGN-1
    float z = 0.f, e2 = 0.f;
#pragma unroll
    for (int s = 0; s < NSEG; s++) {
        z += Zpart[(size_t)s * BGN + i];
        e2 += E2part[(size_t)s * BGN + i];
    }
    float zi = 1.f / z;
    Zinv[i] = zi;
    float r = e2 * zi * zi;
#pragma unroll
    for (int m = 1; m < 64; m <<= 1) r += __shfl_xor(r, m, 64);
    if ((threadIdx.x & 63) == 0) atomicAdd(&S2[i / NQ], r);
}

// ---- pass 2: softmax-normalize + instnorm + *W + PV ----------------------
// grid (49 nblk, 8 g, 4 b), block 256 (4 independent waves, each 16 rows).
// L: tiled layout -> one sequential 1KB wave-load per 32-o chunk.
// W: coalesced group loads (4 rows x 256B per instr) staged through
//    per-wave padded LDS (stride 70 -> max 4-way conflict), dbuf, no barriers.
// V: per-lane loads (L2-resident), register ping-pong.
__global__ __launch_bounds__(256) void pv_kernel(const _Float16* __restrict__ Lt,
        const float* __restrict__ W, const _Float16* __restrict__ vT,
        const float* __restrict__ Zinv, const float* __restrict__ S2,
        _Float16* __restrict__ outp) {
    __shared__ float Ws[4][2][16 * 70];
    const int b = blockIdx.z, g = blockIdx.y;
    const int tid = threadIdx.x;
    const int wv = tid >> 6, lane = tid & 63, l15 = lane & 15, quad = lane >> 4;
    const int n0 = blockIdx.x * 64 + wv * 16;
    const int bg = b * 8 + g;
    const float mm = 1.f / (float)OQ;
    const float rv = rsqrtf(S2[bg] * (1.f / ((float)NQ * (float)OQ)) - mm * mm + 1e-5f);
    const float czr = Zinv[bg * NQ + n0 + l15] * rv;
    const float rm = rv * mm;
    // tiled-L: fully sequential stream per wave
    const _Float16* Lb = Lt + (((size_t)bg * 196 + (n0 >> 4)) * 49) * 256 + lane * 8;
    // W coalesced-group pointer: row n0 + (lane>>4) (+4i), col (lane&15)*4
    const float* Wg = W + ((size_t)bg * NQ + n0 + (lane >> 4)) * OQ + (lane & 15) * 4;
    // W per-row pointer (tail only)
    const float* Wrow = W + ((size_t)bg * NQ + n0 + l15) * OQ;
    const _Float16* vb = vT + (size_t)bg * HD * OQ + (size_t)l15 * OQ;
    float* WsW = &Ws[wv][0][0];
    const float* WsR = &Ws[wv][0][0] + l15 * 70 + quad * 8;

    fx4 wreg[4];
    half8 lA, lB, vA0, vA1, vA2, vA3, vB0, vB1, vB2, vB3;
    fx4 acc0 = fx4{0.f, 0.f, 0.f, 0.f};
    fx4 acc1 = fx4{0.f, 0.f, 0.f, 0.f};
    fx4 acc2 = fx4{0.f, 0.f, 0.f, 0.f};
    fx4 acc3 = fx4{0.f, 0.f, 0.f, 0.f};

#define LOADWG(g2)                                                           \
    {                                                                        \
        _Pragma("unroll") for (int i = 0; i < 4; i++)                        \
            wreg[i] = *(const fx4*)(Wg + (size_t)(4 * i) * OQ + (g2) * 64);  \
    }
#define DSWR(ph)                                                             \
    {                                                                        \
        _Pragma("unroll") for (int i = 0; i < 4; i++)                        \
            *(fx4*)(WsW + (ph) * (16 * 70) + ((lane >> 4) + 4 * i) * 70 +    \
                    (lane & 15) * 4) = wreg[i];                              \
    }
#define LOADL(c, d)                                                          \
    {                                                                        \
        if ((c) < 24 || lane < 32) d = *(const half8*)(Lb + (c) * 512);      \
        else d = h8z();                                                      \
    }
#define LOADV(c, d0, d1, d2, d3)                                             \
    {                                                                        \
        int kb = (c) * 32 + quad * 8;                                        \
        if (kb < OQ) {                                                       \
            d0 = *(const half8*)(vb + (size_t)(0 * 16) * OQ + kb);           \
            d1 = *(const half8*)(vb + (size_t)(1 * 16) * OQ + kb);           \
            d2 = *(const half8*)(vb + (size_t)(2 * 16) * OQ + kb);           \
            d3 = *(const half8*)(vb + (size_t)(3 * 16) * OQ + kb);           \
        } else { d0 = h8z(); d1 = h8z(); d2 = h8z(); d3 = h8z(); }           \
    }
#define COMPUTE_W(sL, wf0, wf1, s0, s1, s2, s3)                              \
    {                                                                        \
        half8 aH;                                                            \
        _Pragma("unroll") for (int j = 0; j < 8; j++) {                      \
            float e = __expf((float)sL[j]);                                  \
            float a = e * czr - rm;                                          \
            float wx = (j < 4) ? wf0[j] : wf1[j - 4];                        \
            aH[j] = (_Float16)(a * wx);                                      \
        }                                                                    \
        acc0 = MFMA16(aH, s0, acc0);                                         \
        acc1 = MFMA16(aH, s1, acc1);                                         \
        acc2 = MFMA16(aH, s2, acc2);                                         \
        acc3 = MFMA16(aH, s3, acc3);                                         \
    }

    // prologue: group0 -> LDS phase0; group1 -> wreg; chunk0 data -> regs
    LOADWG(0);
    LOADL(0, lA);
    LOADV(0, vA0, vA1, vA2, vA3);
    DSWR(0);
    LOADWG(1);

#pragma unroll 1
    for (int pi = 0; pi < 12; ++pi) {
        const int phC = pi & 1, phN = phC ^ 1;
        if (pi <= 10) DSWR(phN);       // stage group pi+1 into LDS
        if (pi <= 9) LOADWG(pi + 2);   // prefetch group pi+2 into regs
        const int c0 = 2 * pi;
        LOADL(c0 + 1, lB);
        LOADV(c0 + 1, vB0, vB1, vB2, vB3);
        {
            const float* wr = WsR + phC * (16 * 70);
            fx4 wf0 = *(const fx4*)(wr);
            fx4 wf1 = *(const fx4*)(wr + 4);
            COMPUTE_W(lA, wf0, wf1, vA0, vA1, vA2, vA3);
        }
        LOADL(c0 + 2, lA);
        LOADV(c0 + 2, vA0, vA1, vA2, vA3);
        {
            const float* wr = WsR + phC * (16 * 70) + 32;
            fx4 wf0 = *(const fx4*)(wr);
            fx4 wf1 = *(const fx4*)(wr + 4);
            COMPUTE_W(lB, wf0, wf1, vB0, vB1, vB2, vB3);
        }
    }
    // tail chunk 24 (o 768..783): lA/vA loaded (guarded) in last iteration
    {
        fx4 wt0 = fx4{0.f, 0.f, 0.f, 0.f};
        fx4 wt1 = fx4{0.f, 0.f, 0.f, 0.f};
        int kb = 768 + quad * 8;
        if (kb < OQ) {
            wt0 = *(const fx4*)(Wrow + kb);
            wt1 = *(const fx4*)(Wrow + kb + 4);
        }
        COMPUTE_W(lA, wt0, wt1, vA0, vA1, vA2, vA3);
    }
#undef LOADWG
#undef DSWR
#undef LOADL
#undef LOADV
#undef COMPUTE_W

    fx4 acc[4] = {acc0, acc1, acc2, acc3};
#pragma unroll
    for (int ds = 0; ds < 4; ds++)
#pragma unroll
        for (int e = 0; e < 4; e++) {
            int n = n0 + quad * 4 + e;
            int c = g * 64 + ds * 16 + l15;
            outp[((size_t)b * NQ + n) * 512 + c] = (_Float16)acc[ds][e];
        }
}

// ---- proj GEMM 64x64 tiles: M=512 channels, N=3136 per b, bias, fp32 out -
// Same T3 2-phase + global_load_lds + swizzle as gemm_qkv.
__global__ __launch_bounds__(256) void gemm_proj(const _Float16* __restrict__ A,
        const _Float16* __restrict__ Ball, const float* __restrict__ bias,
        float* __restrict__ Oall) {
    __shared__ _Float16 As[2][64 * 64];
    __shared__ _Float16 Bs[2][64 * 64];
    const int b = blockIdx.z;
    const _Float16* Bm = Ball + (size_t)b * NQ * 512;
    float* O = Oall + (size_t)b * CC * NQ;
    const int m0 = blockIdx.x * 64, n0 = blockIdx.y * 64;
    const int tid = threadIdx.x;
    const int lane = tid & 63, wv = tid >> 6;
    const int wm = (wv >> 1) * 32, wn = (wv & 1) * 32;
    const int l15 = lane & 15, quad = lane >> 4;
    fx4 acc[2][2];
#pragma unroll
    for (int i = 0; i < 2; i++)
#pragma unroll
        for (int j = 0; j < 2; j++) acc[i][j] = fx4{0.f, 0.f, 0.f, 0.f};

#define STAGEP(bf, kk)                                                       \
    {                                                                        \
        _Pragma("unroll") for (int i = 0; i < 2; i++) {                      \
            int id = tid + 256 * i;                                          \
            int r = id >> 3, gg = id & 7;                                    \
            int gs = gg ^ (r & 7);                                           \
            glds16(A + (size_t)(m0 + r) * 512 + (kk) + gs * 8,               \
                   &As[bf][(id & ~63) * 8]);                                 \
            glds16(Bm + (size_t)(n0 + r) * 512 + (kk) + gs * 8,              \
                   &Bs[bf][(id & ~63) * 8]);                                 \
        }                                                                    \
    }

    STAGEP(0, 0);
    __syncthreads();
    for (int kt = 0; kt < 8; kt++) {
        const int cur = kt & 1;
        if (kt < 7) STAGEP(cur ^ 1, (kt + 1) * 64);
#pragma unroll
        for (int ks = 0; ks < 2; ks++) {
            half8 af[2], bf[2];
#pragma unroll
            for (int s = 0; s < 2; s++) {
                int ra = wm + s * 16 + l15;
                int rb = wn + s * 16 + l15;
                af[s] = *(const half8*)(&As[cur][ra * 64 + ((ks * 4 + quad) ^ (ra & 7)) * 8]);
                bf[s] = *(const half8*)(&Bs[cur][rb * 64 + ((ks * 4 + quad) ^ (rb & 7)) * 8]);
            }
#pragma unroll
            for (int i = 0; i < 2; i++)
#pragma unroll
                for (int j = 0; j < 2; j++)
                    acc[i][j] = MFMA16(af[i], bf[j], acc[i][j]);
        }
        __syncthreads();
    }
#undef STAGEP

#pragma unroll
    for (int i = 0; i < 2; i++)
#pragma unroll
        for (int j = 0; j < 2; j++) {
            int col = n0 + wn + j * 16 + l15;
#pragma unroll
            for (int e = 0; e < 4; e++) {
                int row = m0 + wm + i * 16 + quad * 4 + e;
                O[(size_t)row * NQ + col] = acc[i][j][e] + bias[row];
            }
        }
}

extern "C" void kernel_launch(void* const* d_in, const int* in_sizes, int n_in,
                              void* d_out, int out_size, void* d_ws, size_t ws_size,
                              hipStream_t stream) {
    const float* x = (const float*)d_in[0];
    const float* aw = (const float*)d_in[1];
    const float* q_w = (const float*)d_in[2];
    const float* k_w = (const float*)d_in[3];
    const float* v_w = (const float*)d_in[4];
    const float* sr_w = (const float*)d_in[5];
    const float* sr_b = (const float*)d_in[6];
    const float* ln_g = (const float*)d_in[7];
    const float* ln_b = (const float*)d_in[8];
    const float* tc_w = (const float*)d_in[9];
    const float* tc_b = (const float*)d_in[10];
    const float* p_w = (const float*)d_in[11];
    const float* p_b = (const float*)d_in[12];
    float* out = (float*)d_out;

    char* p = (char*)d_ws;
    auto take = [&](size_t bytes) -> char* {
        char* r = p;
        p += (bytes + 255) & ~(size_t)255;
        return r;
    };
    _Float16* qw16 = (_Float16*)take(512 * 512 * 2);  // qw,kw,vw,pw contiguous
    _Float16* kw16 = (_Float16*)take(512 * 512 * 2);
    _Float16* vw16 = (_Float16*)take(512 * 512 * 2);
    _Float16* pw16 = (_Float16*)take(512 * 512 * 2);
    _Float16* xf16 = (_Float16*)take((size_t)BN * NQ * CC * 2);
    float* xsc = (float*)take((size_t)BN * OQ * CC * 4);
    _Float16* xs16 = (_Float16*)take((size_t)BN * OQ * CC * 2);
    _Float16* q16 = (_Float16*)take((size_t)BN * NQ * CC * 2);
    _Float16* k16 = (_Float16*)take((size_t)BN * OQ * CC * 2);
    _Float16* vT = (_Float16*)take((size_t)BN * OQ * CC * 2);
    _Float16* outp = (_Float16*)take((size_t)BN * NQ * CC * 2);
    float* Zpart = (float*)take((size_t)NSEG * BGN * 4);
    float* E2part = (float*)take((size_t)NSEG * BGN * 4);
    float* S2 = (float*)take(32 * 4);
    float* Zinv = (float*)take((size_t)BGN * 4);
    _Float16* L = (_Float16*)take((size_t)BN * NH * NQ * OQ * 2);

    // weights to fp16 (S2 zeroed here too)
    cvt4_kernel<<<dim3(1024, 4), 256, 0, stream>>>(q_w, k_w, v_w, p_w, qw16, S2);
    // x transpose to (B,NQ,C) fp16
    xpose_kernel<<<dim3(98, 16, BN), dim3(32, 8), 0, stream>>>(x, xf16);
    // spatial reduction conv + LN
    dw_kernel<<<dim3(32, 28, BN), dim3(28, 16), 0, stream>>>(x, sr_w, sr_b, xsc);
    ln_kernel<<<BN * OQ, 256, 0, stream>>>(xsc, ln_g, ln_b, xs16);
    // fused q/k/v projections (v written directly as vT)
    gemm_qkv<<<dim3(196, 8, 3), 256, 0, stream>>>(xf16, xs16, qw16, q16, k16, vT);
    // phase 1: logits (tiled L) + partial softmax stats
    qk_mix<<<dim3(49, 7, BN), 256, 0, stream>>>(q16, k16, tc_w, tc_b, L, Zpart, E2part);
    zfin_kernel<<<BGN / 256, 256, 0, stream>>>(Zpart, E2part, Zinv, S2);
    // phase 2: normalize + instnorm + attn_weights + PV (stream-coarsened)
    pv_kernel<<<dim3(49, 8, BN), 256, 0, stream>>>(L, aw, vT, Zinv, S2, outp);
    // output projection + bias, written directly in (B,C,H,W)
    gemm_proj<<<dim3(8, 49, BN), 256, 0, stream>>>(pw16, outp, p_b, out);
}

// Round 5
// 684.885 us; speedup vs baseline: 1.0321x; 1.0321x over previous
//
#include <hip/hip_runtime.h>

typedef _Float16 half8 __attribute__((ext_vector_type(8)));
typedef _Float16 half4 __attribute__((ext_vector_type(4)));
typedef float fx4 __attribute__((ext_vector_type(4)));

#define MFMA16(a,b,c) __builtin_amdgcn_mfma_f32_16x16x32_f16(a,b,c,0,0,0)

#define BN 4
#define CC 512
#define HH 56
#define WW 56
#define NQ 3136
#define OQ 784
#define NH 8
#define HD 64
#define NSEG 7
#define BGN (BN * NH * NQ)   // 100352

__device__ inline half8 h8z() {
    half8 v;
#pragma unroll
    for (int j = 0; j < 8; j++) v[j] = (_Float16)0.f;
    return v;
}

// async global->LDS, 16B per lane; LDS dest must be wave-uniform base,
// lanes land at base + lane*16 (linear). Source addr is per-lane.
__device__ __forceinline__ void glds16(const void* g, void* l) {
    __builtin_amdgcn_global_load_lds(
        (__attribute__((address_space(1))) const unsigned int*)g,
        (__attribute__((address_space(3))) unsigned int*)l, 16, 0, 0);
}

// ---- convert 4 fp32 weight mats -> fp16 (contiguous dsts); zero S2 -------
__global__ void cvt4_kernel(const float* __restrict__ a, const float* __restrict__ b,
                            const float* __restrict__ c, const float* __restrict__ d,
                            _Float16* __restrict__ o, float* __restrict__ S2) {
    if (blockIdx.x == 0 && blockIdx.y == 0 && threadIdx.x < 32) S2[threadIdx.x] = 0.f;
    int y = blockIdx.y;
    const float* s = (y == 0) ? a : (y == 1) ? b : (y == 2) ? c : d;
    int i = blockIdx.x * 256 + threadIdx.x;
    o[(size_t)y * 262144 + i] = (_Float16)s[i];
}

// ---- x (B,C,H*W) -> xf16 (B, NQ, C) fp16 (tiled transpose) ---------------
__global__ void xpose_kernel(const float* __restrict__ x, _Float16* __restrict__ xf) {
    __shared__ float t[32][33];
    int n0 = blockIdx.x * 32, c0 = blockIdx.y * 32, b = blockIdx.z;
    int tx = threadIdx.x, ty = threadIdx.y;
#pragma unroll
    for (int i = 0; i < 4; i++)
        t[ty + 8 * i][tx] = x[((size_t)(b * CC) + c0 + ty + 8 * i) * NQ + n0 + tx];
    __syncthreads();
#pragma unroll
    for (int i = 0; i < 4; i++)
        xf[((size_t)(b * NQ) + n0 + ty + 8 * i) * CC + c0 + tx] = (_Float16)t[tx][ty + 8 * i];
}

// ---- depthwise conv 3x3 s2 p1 + bias -> xsc (B, OQ, C) fp32 --------------
__global__ void dw_kernel(const float* __restrict__ x, const float* __restrict__ w,
                          const float* __restrict__ bias, float* __restrict__ xsc) {
    int cb = blockIdx.x, oy = blockIdx.y, b = blockIdx.z;
    int tx = threadIdx.x, ty = threadIdx.y;
    int c = cb * 16 + ty;
    float a = bias[c];
    const float* xp = x + ((size_t)(b * CC + c) * HH) * WW;
#pragma unroll
    for (int ky = 0; ky < 3; ky++) {
        int iy = 2 * oy - 1 + ky;
        if (iy < 0 || iy >= HH) continue;
#pragma unroll
        for (int kx = 0; kx < 3; kx++) {
            int ix = 2 * tx - 1 + kx;
            if (ix < 0 || ix >= WW) continue;
            a += xp[iy * WW + ix] * w[c * 9 + ky * 3 + kx];
        }
    }
    __shared__ float tile[28][17];
    tile[tx][ty] = a;
    __syncthreads();
    int lin = ty * 28 + tx;
    int oi = lin >> 4, ci = lin & 15;
    xsc[((size_t)(b * OQ) + oy * 28 + oi) * CC + cb * 16 + ci] = tile[oi][ci];
}

// ---- LayerNorm over C -> xs16 (B*OQ, C) fp16 -----------------------------
__global__ __launch_bounds__(256) void ln_kernel(const float* __restrict__ xsc,
        const float* __restrict__ g, const float* __restrict__ bb,
        _Float16* __restrict__ xs16) {
    int row = blockIdx.x;
    const float* rp = xsc + (size_t)row * CC;
    int t = threadIdx.x;
    float v0 = rp[t], v1 = rp[t + 256];
    float s = v0 + v1, ss = v0 * v0 + v1 * v1;
#pragma unroll
    for (int m = 1; m < 64; m <<= 1) {
        s += __shfl_xor(s, m, 64);
        ss += __shfl_xor(ss, m, 64);
    }
    __shared__ float red[8];
    int wv = t >> 6;
    if ((t & 63) == 0) { red[wv] = s; red[4 + wv] = ss; }
    __syncthreads();
    s = red[0] + red[1] + red[2] + red[3];
    ss = red[4] + red[5] + red[6] + red[7];
    float mean = s * (1.f / 512.f);
    float var = ss * (1.f / 512.f) - mean * mean;
    float rs = rsqrtf(var + 1e-5f);
    xs16[(size_t)row * CC + t] = (_Float16)((v0 - mean) * rs * g[t] + bb[t]);
    xs16[(size_t)row * CC + t + 256] = (_Float16)((v1 - mean) * rs * g[t + 256] + bb[t + 256]);
}

// ---- fused q/k/v projections, 64x64 tiles, K=512 NT ----------------------
// grid (196, 8, 3). T3 2-phase: global_load_lds (16B) + LDS dbuf, one
// barrier per K-tile; XOR-swizzled source (granule ^ row&7) keeps
// ds_read_b128 frag reads 2-way (free) without padding.
__global__ __launch_bounds__(256) void gemm_qkv(const _Float16* __restrict__ xf,
        const _Float16* __restrict__ xs, const _Float16* __restrict__ w4,
        _Float16* __restrict__ q16, _Float16* __restrict__ k16, _Float16* __restrict__ vT) {
    const int which = blockIdx.z;
    if (which && blockIdx.x >= 49) return;
    const _Float16* A = which ? xs : xf;
    const _Float16* Bw = w4 + (size_t)which * 262144;
    __shared__ _Float16 As[2][64 * 64];
    __shared__ _Float16 Bs[2][64 * 64];
    const int m0 = blockIdx.x * 64, n0 = blockIdx.y * 64;
    const int tid = threadIdx.x;
    const int lane = tid & 63, wv = tid >> 6;
    const int wm = (wv >> 1) * 32, wn = (wv & 1) * 32;
    const int l15 = lane & 15, quad = lane >> 4;
    fx4 acc[2][2];
#pragma unroll
    for (int i = 0; i < 2; i++)
#pragma unroll
        for (int j = 0; j < 2; j++) acc[i][j] = fx4{0.f, 0.f, 0.f, 0.f};

#define STAGEG(bf, kk)                                                       \
    {                                                                        \
        _Pragma("unroll") for (int i = 0; i < 2; i++) {                      \
            int id = tid + 256 * i;                                          \
            int r = id >> 3, gg = id & 7;                                    \
            int gs = gg ^ (r & 7);                                           \
            glds16(A + (size_t)(m0 + r) * 512 + (kk) + gs * 8,               \
                   &As[bf][(id & ~63) * 8]);                                 \
            glds16(Bw + (size_t)(n0 + r) * 512 + (kk) + gs * 8,              \
                   &Bs[bf][(id & ~63) * 8]);                                 \
        }                                                                    \
    }

    STAGEG(0, 0);
    __syncthreads();
    for (int kt = 0; kt < 8; kt++) {
        const int cur = kt & 1;
        if (kt < 7) STAGEG(cur ^ 1, (kt + 1) * 64);
#pragma unroll
        for (int ks = 0; ks < 2; ks++) {
            half8 af[2], bf[2];
#pragma unroll
            for (int s = 0; s < 2; s++) {
                int ra = wm + s * 16 + l15;
                int rb = wn + s * 16 + l15;
                af[s] = *(const half8*)(&As[cur][ra * 64 + ((ks * 4 + quad) ^ (ra & 7)) * 8]);
                bf[s] = *(const half8*)(&Bs[cur][rb * 64 + ((ks * 4 + quad) ^ (rb & 7)) * 8]);
            }
#pragma unroll
            for (int i = 0; i < 2; i++)
#pragma unroll
                for (int j = 0; j < 2; j++)
                    acc[i][j] = MFMA16(af[i], bf[j], acc[i][j]);
        }
        __syncthreads();
    }
#undef STAGEG

    if (which < 2) {
        _Float16* O = which ? k16 : q16;
#pragma unroll
        for (int i = 0; i < 2; i++)
#pragma unroll
            for (int j = 0; j < 2; j++) {
                int col = n0 + wn + j * 16 + l15;
#pragma unroll
                for (int e = 0; e < 4; e++) {
                    int row = m0 + wm + i * 16 + quad * 4 + e;
                    O[(size_t)row * 512 + col] = (_Float16)acc[i][j][e];
                }
            }
    } else {
        // vT[(b*8 + c/64)*64 + c%64][o]; 4 consecutive o -> packed 8B store
#pragma unroll
        for (int i = 0; i < 2; i++) {
            int row = m0 + wm + i * 16 + quad * 4;  // b*784 + o, multiple of 4
            int b = row / OQ;
            int o = row - b * OQ;
#pragma unroll
            for (int j = 0; j < 2; j++) {
                int c = n0 + wn + j * 16 + l15;
                half4 pk;
#pragma unroll
                for (int e = 0; e < 4; e++) pk[e] = (_Float16)acc[i][j][e];
                *(half4*)(vT + ((size_t)(b * NH + (c >> 6)) * HD + (c & 63)) * OQ + o) = pk;
            }
        }
    }
}

// ---- QK^T + head-mix + logit write (TILED layout) + partial Z / E2 -------
// grid (49 nblk, 7 oseg, 4 b), block 256 (4 waves, each a 16-row n-subtile)
// K-tile staging: global_load_lds + dbuf, ONE barrier per ot; source
// pre-swizzled (granule low3 ^ row&7) so bF ds_read_b128 is 2-way (free).
// L layout: 16n x 16o tiles -> pv reads one contiguous 1KB wave-load/chunk.
__global__ __launch_bounds__(256) void qk_mix(const _Float16* __restrict__ q16,
        const _Float16* __restrict__ k16, const float* __restrict__ tcw,
        const float* __restrict__ tcb, _Float16* __restrict__ L,
        float* __restrict__ Zpart, float* __restrict__ E2part) {
    __shared__ _Float16 kl[2][16 * 512];
    __shared__ float tcs[64];
    __shared__ float tbb[8];
    const int b = blockIdx.z, oseg = blockIdx.y, ob = oseg * 112;
    const int tid = threadIdx.x;
    const int wv = tid >> 6, lane = tid & 63, l15 = lane & 15, quad = lane >> 4;
    const int n0 = blockIdx.x * 64 + wv * 16;
    if (tid < 64) tcs[tid] = tcw[tid] * 0.125f;  // fold scale hd^-0.5
    else if (tid < 72) tbb[tid - 64] = tcb[tid - 64];

    half8 aF[8][2];
    const _Float16* qrow = q16 + ((size_t)(b * NQ + n0 + l15)) * 512;
#pragma unroll
    for (int h = 0; h < 8; h++)
#pragma unroll
        for (int ks = 0; ks < 2; ks++)
            aF[h][ks] = *(const half8*)(qrow + h * 64 + ks * 32 + quad * 8);

    float z[8][4], s2[8][4];
#pragma unroll
    for (int g = 0; g < 8; g++)
#pragma unroll
        for (int e = 0; e < 4; e++) { z[g][e] = 0.f; s2[g][e] = 0.f; }

#define STAGEK(bf, oo)                                                       \
    {                                                                        \
        const _Float16* kbp = k16 + ((size_t)(b * OQ + (oo))) * 512;         \
        _Pragma("unroll") for (int i = 0; i < 4; i++) {                      \
            int id = tid + 256 * i;                                          \
            int r = id >> 6, g16 = id & 63;                                  \
            int gs = (g16 & 56) | ((g16 & 7) ^ (r & 7));                     \
            glds16(kbp + (size_t)r * 512 + gs * 8, &kl[bf][(id & ~63) * 8]); \
        }                                                                    \
    }

    STAGEK(0, ob);
    __syncthreads();  // buf0 ready; also covers tcs/tbb init

    for (int ot = 0; ot < 7; ot++) {
        const int cur = ot & 1;
        if (ot < 6) STAGEK(cur ^ 1, ob + (ot + 1) * 16);  // overlap w/ compute
        int o0 = ob + ot * 16;
        fx4 s[8];
#pragma unroll
        for (int h = 0; h < 8; h++) {
            fx4 a = fx4{0.f, 0.f, 0.f, 0.f};
#pragma unroll
            for (int ks = 0; ks < 2; ks++) {
                int colg = h * 8 + ks * 4 + quad;
                int rg = (colg & 56) | ((colg & 7) ^ (l15 & 7));
                half8 bF = *(const half8*)(&kl[cur][l15 * 512 + rg * 8]);
                a = MFMA16(aF[h][ks], bF, a);
            }
            s[h] = a;
        }
#pragma unroll
        for (int g = 0; g < 8; g++) {
            size_t tb = (((size_t)(b * 8 + g) * 196 + (n0 >> 4)) * 49 + (o0 >> 4)) * 256
                        + (l15 >> 3) * 128 + (l15 & 7);
#pragma unroll
            for (int e = 0; e < 4; e++) {
                float v = tbb[g];
#pragma unroll
                for (int h = 0; h < 8; h++) v += tcs[g * 8 + h] * s[h][e];
                _Float16 vh = (_Float16)v;
                float vr = (float)vh;  // rounded value so Z matches pass 2 exactly
                float ex = __expf(vr);
                z[g][e] += ex;
                s2[g][e] += ex * ex;
                L[tb + (quad * 4 + e) * 8] = vh;
            }
        }
        __syncthreads();  // drains stage of buf cur^1 -> ready next ot
    }
#undef STAGEK

#pragma unroll
    for (int m = 1; m < 16; m <<= 1) {
#pragma unroll
        for (int g = 0; g < 8; g++)
#pragma unroll
            for (int e = 0; e < 4; e++) {
                z[g][e] += __shfl_xor(z[g][e], m, 64);
                s2[g][e] += __shfl_xor(s2[g][e], m, 64);
            }
    }
    if (l15 < 8) {
        int g = l15;
        size_t base = (size_t)oseg * BGN + (size_t)(b * 8 + g) * NQ + n0 + quad * 4;
#pragma unroll
        for (int e = 0; e < 4; e++) {
            Zpart[base + e] = z[g][e];
            E2part[base + e] = s2[g][e];
        }
    }
}

// ---- sum partials: Zinv per row, S2[b,g] global --------------------------
__global__ __launch_bounds__(256) void zfin_kernel(const float* __restrict__ Zpart,
        const float* __restrict__ E2part, float* __restrict__ Zinv, float* __restrict__ S2) {
    int i = blockIdx.x * 256 + threadIdx.x;  // 0..BGN-1
    float z = 0.f, e2 = 0.f;
#pragma unroll
    for (int s = 0; s < NSEG; s++) {
        z += Zpart[(size_t)s * BGN + i];
        e2 += E2part[(size_t)s * BGN + i];
    }
    float zi = 1.f / z;
    Zinv[i] = zi;
    float r = e2 * zi * zi;
#pragma unroll
    for (int m = 1; m < 64; m <<= 1) r += __shfl_xor(r, m, 64);
    if ((threadIdx.x & 63) == 0) atomicAdd(&S2[i / NQ], r);
}

// ---- pass 2: softmax-normalize + instnorm + *W + PV ----------------------
// block 256 (4 independent waves, each 16 rows).
// XCD remap: f%8 -> head-group g, so each XCD's L2 keeps its 4 V slices.
// L: tiled layout, nt loads, prefetch distance 2 chunks.
// W: nt group loads (read-once stream, don't thrash L2/L3) -> per-wave LDS.
// V: per-lane loads (L2-resident via swizzle), register ping-pong.
__global__ __launch_bounds__(256) void pv_kernel(const _Float16* __restrict__ Lt,
        const float* __restrict__ W, const _Float16* __restrict__ vT,
        const float* __restrict__ Zinv, const float* __restrict__ S2,
        _Float16* __restrict__ outp) {
    __shared__ float Ws[4][2][16 * 70];
    // bijective XCD-aware remap (1568 = 8*196): xcd ~ f%8 owns one g
    const int f = blockIdx.x + 49 * (blockIdx.y + 8 * blockIdx.z);
    const int g = f & 7;
    const int r = f >> 3;        // 0..195
    const int b = r & 3;
    const int nblk = r >> 2;     // 0..48
    const int tid = threadIdx.x;
    const int wv = tid >> 6, lane = tid & 63, l15 = lane & 15, quad = lane >> 4;
    const int n0 = nblk * 64 + wv * 16;
    const int bg = b * 8 + g;
    const float mm = 1.f / (float)OQ;
    const float rv = rsqrtf(S2[bg] * (1.f / ((float)NQ * (float)OQ)) - mm * mm + 1e-5f);
    const float czr = Zinv[bg * NQ + n0 + l15] * rv;
    const float rm = rv * mm;
    // tiled-L: fully sequential stream per wave
    const _Float16* Lb = Lt + (((size_t)bg * 196 + (n0 >> 4)) * 49) * 256 + lane * 8;
    // W coalesced-group pointer: row n0 + (lane>>4) (+4i), col (lane&15)*4
    const float* Wg = W + ((size_t)bg * NQ + n0 + (lane >> 4)) * OQ + (lane & 15) * 4;
    // W per-row pointer (tail only)
    const float* Wrow = W + ((size_t)bg * NQ + n0 + l15) * OQ;
    const _Float16* vb = vT + (size_t)bg * HD * OQ + (size_t)l15 * OQ;
    float* WsW = &Ws[wv][0][0];
    const float* WsR = &Ws[wv][0][0] + l15 * 70 + quad * 8;

    fx4 wreg[4];
    half8 lq[2][2];                       // L pairs, prefetch distance 2
    half8 vE0, vE1, vE2, vE3;             // V even-chunk set
    half8 vO0, vO1, vO2, vO3;             // V odd-chunk set
    fx4 acc0 = fx4{0.f, 0.f, 0.f, 0.f};
    fx4 acc1 = fx4{0.f, 0.f, 0.f, 0.f};
    fx4 acc2 = fx4{0.f, 0.f, 0.f, 0.f};
    fx4 acc3 = fx4{0.f, 0.f, 0.f, 0.f};

#define LOADWG(g2)                                                           \
    {                                                                        \
        _Pragma("unroll") for (int i = 0; i < 4; i++)                        \
            wreg[i] = __builtin_nontemporal_load(                            \
                (const fx4*)(Wg + (size_t)(4 * i) * OQ + (g2) * 64));        \
    }
#define DSWR(ph)                                                             \
    {                                                                        \
        _Pragma("unroll") for (int i = 0; i < 4; i++)                        \
            *(fx4*)(WsW + (ph) * (16 * 70) + ((lane >> 4) + 4 * i) * 70 +    \
                    (lane & 15) * 4) = wreg[i];                              \
    }
#define LOADL(c, d)                                                          \
    {                                                                        \
        if ((c) < 25 && ((c) < 24 || lane < 32))                             \
            d = __builtin_nontemporal_load((const half8*)(Lb + (size_t)(c) * 512)); \
        else d = h8z();                                                      \
    }
#define LOADV(c, d0, d1, d2, d3)                                             \
    {                                                                        \
        int kb = (c) * 32 + quad * 8;                                        \
        if (kb < OQ) {                                                       \
            d0 = *(const half8*)(vb + (size_t)(0 * 16) * OQ + kb);           \
            d1 = *(const half8*)(vb + (size_t)(1 * 16) * OQ + kb);           \
            d2 = *(const half8*)(vb + (size_t)(2 * 16) * OQ + kb);           \
            d3 = *(const half8*)(vb + (size_t)(3 * 16) * OQ + kb);           \
        } else { d0 = h8z(); d1 = h8z(); d2 = h8z(); d3 = h8z(); }           \
    }
#define COMPUTE_W(sL, wf0, wf1, s0, s1, s2, s3)                              \
    {                                                                        \
        half8 aH;                                                            \
        _Pragma("unroll") for (int j = 0; j < 8; j++) {                      \
            float e = __expf((float)sL[j]);                                  \
            float a = e * czr - rm;                                          \
            float wx = (j < 4) ? wf0[j] : wf1[j - 4];                        \
            aH[j] = (_Float16)(a * wx);                                      \
        }                                                                    \
        acc0 = MFMA16(aH, s0, acc0);                                         \
        acc1 = MFMA16(aH, s1, acc1);                                         \
        acc2 = MFMA16(aH, s2, acc2);                                         \
        acc3 = MFMA16(aH, s3, acc3);                                         \
    }

    // prologue: L chunks 0,1 first (deep HBM stream), W group0->LDS,
    // group1->regs, V chunk0.
    LOADL(0, lq[0][0]);
    LOADL(1, lq[0][1]);
    LOADWG(0);
    LOADV(0, vE0, vE1, vE2, vE3);
    DSWR(0);
    LOADWG(1);

#pragma unroll
    for (int pi = 0; pi < 12; ++pi) {
        const int pc = pi & 1, pn = pc ^ 1;
        // L prefetch: next pair (distance 2 chunks from use)
        LOADL(2 * pi + 2, lq[pn][0]);
        LOADL(2 * pi + 3, lq[pn][1]);
        if (pi <= 10) DSWR(pn);        // stage W group pi+1 into LDS
        if (pi <= 9) LOADWG(pi + 2);   // prefetch W group pi+2 into regs
        LOADV(2 * pi + 1, vO0, vO1, vO2, vO3);
        {
            const float* wr = WsR + pc * (16 * 70);
            fx4 wf0 = *(const fx4*)(wr);
            fx4 wf1 = *(const fx4*)(wr + 4);
            COMPUTE_W(lq[pc][0], wf0, wf1, vE0, vE1, vE2, vE3);
        }
        LOADV(2 * pi + 2, vE0, vE1, vE2, vE3);
        {
            const float* wr = WsR + pc * (16 * 70) + 32;
            fx4 wf0 = *(const fx4*)(wr);
            fx4 wf1 = *(const fx4*)(wr + 4);
            COMPUTE_W(lq[pc][1], wf0, wf1, vO0, vO1, vO2, vO3);
        }
    }
    // tail chunk 24: L in lq[0][0] (loaded at pi=11), V in E-set (loaded at pi=11)
    {
        fx4 wt0 = fx4{0.f, 0.f, 0.f, 0.f};
        fx4 wt1 = fx4{0.f, 0.f, 0.f, 0.f};
        int kb = 768 + quad * 8;
        if (kb < OQ) {
            wt0 = __builtin_nontemporal_load((const fx4*)(Wrow + kb));
            wt1 = __builtin_nontemporal_load((const fx4*)(Wrow + kb + 4));
        }
        COMPUTE_W(lq[0][0], wt0, wt1, vE0, vE1, vE2, vE3);
    }
#undef LOADWG
#undef DSWR
#undef LOADL
#undef LOADV
#undef COMPUTE_W

    fx4 acc[4] = {acc0, acc1, acc2, acc3};
#pragma unroll
    for (int ds = 0; ds < 4; ds++)
#pragma unroll
        for (int e = 0; e < 4; e++) {
            int n = n0 + quad * 4 + e;
            int c = g * 64 + ds * 16 + l15;
            outp[((size_t)b * NQ + n) * 512 + c] = (_Float16)acc[ds][e];
        }
}

// ---- proj GEMM 64x64 tiles: M=512 channels, N=3136 per b, bias, fp32 out -
// Same T3 2-phase + global_load_lds + swizzle as gemm_qkv.
__global__ __launch_bounds__(256) void gemm_proj(const _Float16* __restrict__ A,
        const _Float16* __restrict__ Ball, const float* __restrict__ bias,
        float* __restrict__ Oall) {
    __shared__ _Float16 As[2][64 * 64];
    __shared__ _Float16 Bs[2][64 * 64];
    const int b = blockIdx.z;
    const _Float16* Bm = Ball + (size_t)b * NQ * 512;
    float* O = Oall + (size_t)b * CC * NQ;
    const int m0 = blockIdx.x * 64, n0 = blockIdx.y * 64;
    const int tid = threadIdx.x;
    const int lane = tid & 63, wv = tid >> 6;
    const int wm = (wv >> 1) * 32, wn = (wv & 1) * 32;
    const int l15 = lane & 15, quad = lane >> 4;
    fx4 acc[2][2];
#pragma unroll
    for (int i = 0; i < 2; i++)
#pragma unroll
        for (int j = 0; j < 2; j++) acc[i][j] = fx4{0.f, 0.f, 0.f, 0.f};

#define STAGEP(bf, kk)                                                       \
    {                                                                        \
        _Pragma("unroll") for (int i = 0; i < 2; i++) {                      \
            int id = tid + 256 * i;                                          \
            int r = id >> 3, gg = id & 7;                                    \
            int gs = gg ^ (r & 7);                                           \
            glds16(A + (size_t)(m0 + r) * 512 + (kk) + gs * 8,               \
                   &As[bf][(id & ~63) * 8]);                                 \
            glds16(Bm + (size_t)(n0 + r) * 512 + (kk) + gs * 8,              \
                   &Bs[bf][(id & ~63) * 8]);                                 \
        }                                                                    \
    }

    STAGEP(0, 0);
    __syncthreads();
    for (int kt = 0; kt < 8; kt++) {
        const int cur = kt & 1;
        if (kt < 7) STAGEP(cur ^ 1, (kt + 1) * 64);
#pragma unroll
        for (int ks = 0; ks < 2; ks++) {
            half8 af[2], bf[2];
#pragma unroll
            for (int s = 0; s < 2; s++) {
                int ra = wm + s * 16 + l15;
                int rb = wn + s * 16 + l15;
                af[s] = *(const half8*)(&As[cur][ra * 64 + ((ks * 4 + quad) ^ (ra & 7)) * 8]);
                bf[s] = *(const half8*)(&Bs[cur][rb * 64 + ((ks * 4 + quad) ^ (rb & 7)) * 8]);
            }
#pragma unroll
            for (int i = 0; i < 2; i++)
#pragma unroll
                for (int j = 0; j < 2; j++)
                    acc[i][j] = MFMA16(af[i], bf[j], acc[i][j]);
        }
        __syncthreads();
    }
#undef STAGEP

#pragma unroll
    for (int i = 0; i < 2; i++)
#pragma unroll
        for (int j = 0; j < 2; j++) {
            int col = n0 + wn + j * 16 + l15;
#pragma unroll
            for (int e = 0; e < 4; e++) {
                int row = m0 + wm + i * 16 + quad * 4 + e;
                O[(size_t)row * NQ + col] = acc[i][j][e] + bias[row];
            }
        }
}

extern "C" void kernel_launch(void* const* d_in, const int* in_sizes, int n_in,
                              void* d_out, int out_size, void* d_ws, size_t ws_size,
                              hipStream_t stream) {
    const float* x = (const float*)d_in[0];
    const float* aw = (const float*)d_in[1];
    const float* q_w = (const float*)d_in[2];
    const float* k_w = (const float*)d_in[3];
    const float* v_w = (const float*)d_in[4];
    const float* sr_w = (const float*)d_in[5];
    const float* sr_b = (const float*)d_in[6];
    const float* ln_g = (const float*)d_in[7];
    const float* ln_b = (const float*)d_in[8];
    const float* tc_w = (const float*)d_in[9];
    const float* tc_b = (const float*)d_in[10];
    const float* p_w = (const float*)d_in[11];
    const float* p_b = (const float*)d_in[12];
    float* out = (float*)d_out;

    char* p = (char*)d_ws;
    auto take = [&](size_t bytes) -> char* {
        char* r = p;
        p += (bytes + 255) & ~(size_t)255;
        return r;
    };
    _Float16* qw16 = (_Float16*)take(512 * 512 * 2);  // qw,kw,vw,pw contiguous
    _Float16* kw16 = (_Float16*)take(512 * 512 * 2);
    _Float16* vw16 = (_Float16*)take(512 * 512 * 2);
    _Float16* pw16 = (_Float16*)take(512 * 512 * 2);
    _Float16* xf16 = (_Float16*)take((size_t)BN * NQ * CC * 2);
    float* xsc = (float*)take((size_t)BN * OQ * CC * 4);
    _Float16* xs16 = (_Float16*)take((size_t)BN * OQ * CC * 2);
    _Float16* q16 = (_Float16*)take((size_t)BN * NQ * CC * 2);
    _Float16* k16 = (_Float16*)take((size_t)BN * OQ * CC * 2);
    _Float16* vT = (_Float16*)take((size_t)BN * OQ * CC * 2);
    _Float16* outp = (_Float16*)take((size_t)BN * NQ * CC * 2);
    float* Zpart = (float*)take((size_t)NSEG * BGN * 4);
    float* E2part = (float*)take((size_t)NSEG * BGN * 4);
    float* S2 = (float*)take(32 * 4);
    float* Zinv = (float*)take((size_t)BGN * 4);
    _Float16* L = (_Float16*)take((size_t)BN * NH * NQ * OQ * 2);

    // weights to fp16 (S2 zeroed here too)
    cvt4_kernel<<<dim3(1024, 4), 256, 0, stream>>>(q_w, k_w, v_w, p_w, qw16, S2);
    // x transpose to (B,NQ,C) fp16
    xpose_kernel<<<dim3(98, 16, BN), dim3(32, 8), 0, stream>>>(x, xf16);
    // spatial reduction conv + LN
    dw_kernel<<<dim3(32, 28, BN), dim3(28, 16), 0, stream>>>(x, sr_w, sr_b, xsc);
    ln_kernel<<<BN * OQ, 256, 0, stream>>>(xsc, ln_g, ln_b, xs16);
    // fused q/k/v projections (v written directly as vT)
    gemm_qkv<<<dim3(196, 8, 3), 256, 0, stream>>>(xf16, xs16, qw16, q16, k16, vT);
    // phase 1: logits (tiled L) + partial softmax stats
    qk_mix<<<dim3(49, 7, BN), 256, 0, stream>>>(q16, k16, tc_w, tc_b, L, Zpart, E2part);
    zfin_kernel<<<BGN / 256, 256, 0, stream>>>(Zpart, E2part, Zinv, S2);
    // phase 2: normalize + instnorm + attn_weights + PV (XCD-swizzled, nt, deep prefetch)
    pv_kernel<<<dim3(49, 8, BN), 256, 0, stream>>>(L, aw, vT, Zinv, S2, outp);
    // output projection + bias, written directly in (B,C,H,W)
    gemm_proj<<<dim3(8, 49, BN), 256, 0, stream>>>(pw16, outp, p_b, out);
}